// Round 3
// baseline (101.979 us; speedup 1.0000x reference)
//
#include <hip/hip_runtime.h>
#include <math.h>

#define N 8
#define C 256
#define L 512
#define K 100
#define NL (N * L)
#define EPSN 1e-8f

// ws layout: cn[NL*C] f32 (4 MB) | zq[NL*C] fp8-e4m3 (1 MB)
//            | partials[1024] f32 | done_cnt int

typedef float v2f __attribute__((ext_vector_type(2)));

__device__ __forceinline__ unsigned char f2fp8(float x) {
    return (unsigned char)(__builtin_amdgcn_cvt_pk_fp8_f32(x, x, 0, false) & 0xff);
}

// K1: transpose (N,C,L)->(NL,C) + fp32 normalize; c -> fp32 cn, z -> fp8 zq.
// 256 blocks: tile = 256 c's x 32 l's, full-128B-line global reads.
// Block 0 also zeroes the done-counter for K2's last-block reduction.
__global__ __launch_bounds__(256) void prep_kernel(
    const float* __restrict__ z, const float* __restrict__ c,
    unsigned char* __restrict__ zq, float* __restrict__ cn,
    int* __restrict__ done_cnt)
{
    __shared__ float tile[256 * 33];   // [c][l], pad 33: conflict-free
    __shared__ float red[256];
    __shared__ float linv[32];

    if (blockIdx.x == 0 && threadIdx.x == 0) *done_cnt = 0;

    const int b    = blockIdx.x;
    const int is_c = b >= 128;
    const int bb   = b & 127;
    const int n    = bb >> 4;
    const int l0   = (bb & 15) << 5;     // 32 l's per block
    const int ld   = is_c ? (L + 1) : L;
    const float* src = (is_c ? c : z) + (size_t)n * C * ld + (is_c ? 1 : 0) + l0;

    const int t   = threadIdx.x;
    const int lcl = t & 31;              // local l (128B coalesced)
    const int cg  = t >> 5;              // c group

    float ss = 0.f;
    #pragma unroll
    for (int i = 0; i < 32; ++i) {
        const int cidx = i * 8 + cg;
        const float v = src[(size_t)cidx * ld + lcl];
        tile[cidx * 33 + lcl] = v;
        ss += v * v;
    }
    red[t] = ss;
    __syncthreads();
    if (t < 32) {
        float tot = 0.f;
        #pragma unroll
        for (int j = 0; j < 8; ++j) tot += red[j * 32 + t];
        linv[t] = 1.f / fmaxf(sqrtf(tot), EPSN);
    }
    __syncthreads();
    if (is_c) {
        float* dst = cn + (size_t)(n * L + l0) * C;
        #pragma unroll
        for (int j = 0; j < 32; ++j)
            dst[(size_t)j * C + t] = tile[t * 33 + j] * linv[j];   // coalesced
    } else {
        unsigned char* dst = zq + (size_t)(n * L + l0) * C;
        #pragma unroll
        for (int j = 0; j < 32; ++j)
            dst[(size_t)j * C + t] = f2fp8(tile[t * 33 + j] * linv[j]);
    }
}

// 16-channel fp8 dot: cvt_pk gives f32 PAIRS -> accumulate with packed
// v_pk_fma_f32 (v2f ext-vector arith; 2 mul + 6 pk_fma vs 16 scalar fma).
__device__ __forceinline__ float dot16(uint4 zd, float4 ca, float4 cb,
                                       float4 cc, float4 ce)
{
    const v2f c0 = {ca.x, ca.y}, c1 = {ca.z, ca.w};
    const v2f c2 = {cb.x, cb.y}, c3 = {cb.z, cb.w};
    const v2f c4 = {cc.x, cc.y}, c5 = {cc.z, cc.w};
    const v2f c6 = {ce.x, ce.y}, c7 = {ce.z, ce.w};
    v2f q, a0, a1;
    q = __builtin_amdgcn_cvt_pk_f32_fp8(zd.x, false); a0 = q * c0;
    q = __builtin_amdgcn_cvt_pk_f32_fp8(zd.x, true);  a1 = q * c1;
    q = __builtin_amdgcn_cvt_pk_f32_fp8(zd.y, false); a0 += q * c2;
    q = __builtin_amdgcn_cvt_pk_f32_fp8(zd.y, true);  a1 += q * c3;
    q = __builtin_amdgcn_cvt_pk_f32_fp8(zd.z, false); a0 += q * c4;
    q = __builtin_amdgcn_cvt_pk_f32_fp8(zd.z, true);  a1 += q * c5;
    q = __builtin_amdgcn_cvt_pk_f32_fp8(zd.w, false); a0 += q * c6;
    q = __builtin_amdgcn_cvt_pk_f32_fp8(zd.w, true);  a1 += q * c7;
    const v2f a = a0 + a1;
    return a.x + a.y;
}

// Sum one target's 16 partials (4 x float4 from LDS, in-lane, no shfl).
__device__ __forceinline__ float sumrow(const float* qp)
{
    const float4 a0 = *(const float4*)(qp);
    const float4 a1 = *(const float4*)(qp + 4);
    const float4 a2 = *(const float4*)(qp + 8);
    const float4 a3 = *(const float4*)(qp + 12);
    return ((a0.x + a0.y) + (a0.z + a0.w))
         + ((a1.x + a1.y) + (a1.z + a1.w))
         + ((a2.x + a2.y) + (a2.z + a2.w))
         + ((a3.x + a3.y) + (a3.z + a3.w));
}

// Fixed-shift LSE accumulate (logit = 2*cos <= 2) + rare exact-equal mask.
__device__ __forceinline__ void accum_target(
    int t, float dt, int row, const int* __restrict__ negp,
    const float* __restrict__ z, const float* __restrict__ c,
    float& s_acc, float& pos)
{
    const float sim2 = dt * 2.0f;
    if (t == 0) pos = sim2;
    bool use = (t <= K);
    if (use && t >= 1 && sim2 > 1.9f) {  // exact-equal mask (rare path)
        const int idxv = negp[t - 1];
        const int nr = row >> 9, lr = row & 511;
        const int ni = idxv >> 9, li = idxv & 511;
        bool eq = true;
        for (int e = 0; e < C && eq; ++e)
            eq = (c[((size_t)nr * C + e) * (L + 1) + lr + 1]
                  == z[((size_t)ni * C + e) * L + li]);
        if (eq) use = false;             // masked -inf -> contributes 0
    }
    if (use) s_acc += __expf(sim2 - 2.0f);
}

// K2: one wave per row; FOUR targets per gather wave-op (fp8 row = 256B,
// 16 lanes/target x 16B = 16 channels/lane). 104 targets (1 pos + 100 neg
// + 3 pad) in batches of 64 + 40. Phase 2: each lane owns one target,
// 4 in-lane b128 reads, no shfl.
// Tail: uncontended partials[b] release-store + ONE counter atomic per
// block; last block reduces all 1024 partials (rocPRIM pattern) -- saves
// the K3 dispatch without round-1's 1024 same-address float-add pileup.
__global__ __launch_bounds__(256, 4) void logits_kernel(
    const unsigned char* __restrict__ zq, const float* __restrict__ cn,
    const int* __restrict__ neg,
    const float* __restrict__ z, const float* __restrict__ c,
    float* __restrict__ partials, int* __restrict__ done_cnt,
    float* __restrict__ out)
{
    __shared__ float buf[4][26 * 68];   // 16-row + 10-row batch regions
    __shared__ float wterm[4];
    __shared__ int last_flag;
    __shared__ float red4[4];

    const int w = threadIdx.x >> 6, lane = threadIdx.x & 63;
    const int row = __builtin_amdgcn_readfirstlane((int)blockIdx.x * 4 + w);
    const int* __restrict__ negp = neg + (size_t)row * K;
    const int g = lane >> 4;             // target within quad
    const int k = lane & 15;             // 16-channel chunk

    const float* crow = cn + (size_t)row * C + k * 16;
    const float4 ca = *(const float4*)(crow);
    const float4 cb = *(const float4*)(crow + 4);
    const float4 cc = *(const float4*)(crow + 8);
    const float4 ce = *(const float4*)(crow + 12);

    float s_acc = 0.f, pos = 0.f;
    float* __restrict__ pb0 = &buf[w][0];
    float* __restrict__ pb1 = &buf[w][16 * 68];

    // ---- batch 0: targets 0..63 (16 gather wave-ops) ----
    #pragma unroll 8
    for (int r = 0; r < 16; ++r) {
        const int t0 = 4 * r;
        const int i0 = (t0 == 0) ? row
                                 : __builtin_amdgcn_readfirstlane(negp[t0 - 1]);
        const int i1 = __builtin_amdgcn_readfirstlane(negp[t0]);
        const int i2 = __builtin_amdgcn_readfirstlane(negp[t0 + 1]);
        const int i3 = __builtin_amdgcn_readfirstlane(negp[t0 + 2]);
        const int idx = (g == 0) ? i0 : (g == 1) ? i1 : (g == 2) ? i2 : i3;
        const uint4 zd = *(const uint4*)(zq + (size_t)idx * C + k * 16);
        pb0[r * 68 + g * 16 + k] = dot16(zd, ca, cb, cc, ce); // 2-way alias: free
    }
    {   // phase 2: lane owns target t = lane
        const int t = lane;
        const float* qp = pb0 + (lane >> 2) * 68 + (lane & 3) * 16;
        accum_target(t, sumrow(qp), row, negp, z, c, s_acc, pos);
    }

    // ---- batch 1: targets 64..103 (10 gather wave-ops, 101..103 = pad) ----
    #pragma unroll 8
    for (int r = 0; r < 10; ++r) {
        const int t0 = 64 + 4 * r;
        const int i0 = __builtin_amdgcn_readfirstlane(negp[t0 - 1]);
        const int i1 = (t0 + 1 <= K) ? __builtin_amdgcn_readfirstlane(negp[t0]) : row;
        const int i2 = (t0 + 2 <= K) ? __builtin_amdgcn_readfirstlane(negp[t0 + 1]) : row;
        const int i3 = (t0 + 3 <= K) ? __builtin_amdgcn_readfirstlane(negp[t0 + 2]) : row;
        const int idx = (g == 0) ? i0 : (g == 1) ? i1 : (g == 2) ? i2 : i3;
        const uint4 zd = *(const uint4*)(zq + (size_t)idx * C + k * 16);
        pb1[r * 68 + g * 16 + k] = dot16(zd, ca, cb, cc, ce);
    }
    {   // phase 2: lanes 0..39 own targets 64..103; rest masked by t<=K
        const int t = 64 + lane;
        const int pr = (lane >> 2) < 10 ? (lane >> 2) : 0;  // clamp: masked lanes
        const float* qp = pb1 + pr * 68 + (lane & 3) * 16;
        accum_target(t, sumrow(qp), row, negp, z, c, s_acc, pos);
    }

    #pragma unroll
    for (int m = 1; m < 64; m <<= 1) s_acc += __shfl_xor(s_acc, m, 64);
    if (lane == 0) wterm[w] = 2.0f + __logf(s_acc) - pos;
    __syncthreads();

    // ---- tail: publish block partial, last block reduces ----
    if (threadIdx.x == 0) {
        const float bsum = wterm[0] + wterm[1] + wterm[2] + wterm[3];
        __hip_atomic_store(&partials[blockIdx.x], bsum,
                           __ATOMIC_RELEASE, __HIP_MEMORY_SCOPE_AGENT);
        const int old = __hip_atomic_fetch_add(done_cnt, 1,
                           __ATOMIC_ACQ_REL, __HIP_MEMORY_SCOPE_AGENT);
        last_flag = (old == (int)gridDim.x - 1);
    }
    __syncthreads();
    if (last_flag) {
        const int t = threadIdx.x;
        float s = __hip_atomic_load(&partials[t],
                      __ATOMIC_RELAXED, __HIP_MEMORY_SCOPE_AGENT)
                + __hip_atomic_load(&partials[t + 256],
                      __ATOMIC_RELAXED, __HIP_MEMORY_SCOPE_AGENT)
                + __hip_atomic_load(&partials[t + 512],
                      __ATOMIC_RELAXED, __HIP_MEMORY_SCOPE_AGENT)
                + __hip_atomic_load(&partials[t + 768],
                      __ATOMIC_RELAXED, __HIP_MEMORY_SCOPE_AGENT);
        #pragma unroll
        for (int m = 1; m < 64; m <<= 1) s += __shfl_xor(s, m, 64);
        if ((t & 63) == 0) red4[t >> 6] = s;
        __syncthreads();
        if (t == 0)
            out[0] = (red4[0] + red4[1] + red4[2] + red4[3]) * (1.0f / NL);
    }
}

extern "C" void kernel_launch(void* const* d_in, const int* in_sizes, int n_in,
                              void* d_out, int out_size, void* d_ws, size_t ws_size,
                              hipStream_t stream) {
    const float* z = (const float*)d_in[0];
    const float* c = (const float*)d_in[1];
    const int* neg = (const int*)d_in[2];
    float* out = (float*)d_out;

    float* cn = (float*)d_ws;
    unsigned char* zq = (unsigned char*)(cn + (size_t)NL * C);
    float* partials = (float*)(zq + (size_t)NL * C);
    int* done_cnt = (int*)(partials + 1024);

    prep_kernel<<<256, 256, 0, stream>>>(z, c, zq, cn, done_cnt);
    logits_kernel<<<NL / 4, 256, 0, stream>>>(zq, cn, neg, z, c,
                                              partials, done_cnt, out);
}

// Round 4
// 76.845 us; speedup vs baseline: 1.3271x; 1.3271x over previous
//
#include <hip/hip_runtime.h>
#include <math.h>

#define N 8
#define C 256
#define L 512
#define K 100
#define NL (N * L)
#define EPSN 1e-8f

// ws layout: cn[NL*C] f32 (4 MB) | zq[NL*C] fp8-e4m3 (1 MB) | partials[1024] f32

typedef float v2f __attribute__((ext_vector_type(2)));

__device__ __forceinline__ unsigned char f2fp8(float x) {
    return (unsigned char)(__builtin_amdgcn_cvt_pk_fp8_f32(x, x, 0, false) & 0xff);
}

// K1: transpose (N,C,L)->(NL,C) + fp32 normalize; c -> fp32 cn, z -> fp8 zq.
// 256 blocks: tile = 256 c's x 32 l's, full-128B-line global reads.
__global__ __launch_bounds__(256) void prep_kernel(
    const float* __restrict__ z, const float* __restrict__ c,
    unsigned char* __restrict__ zq, float* __restrict__ cn)
{
    __shared__ float tile[256 * 33];   // [c][l], pad 33: conflict-free
    __shared__ float red[256];
    __shared__ float linv[32];

    const int b    = blockIdx.x;
    const int is_c = b >= 128;
    const int bb   = b & 127;
    const int n    = bb >> 4;
    const int l0   = (bb & 15) << 5;     // 32 l's per block
    const int ld   = is_c ? (L + 1) : L;
    const float* src = (is_c ? c : z) + (size_t)n * C * ld + (is_c ? 1 : 0) + l0;

    const int t   = threadIdx.x;
    const int lcl = t & 31;              // local l (128B coalesced)
    const int cg  = t >> 5;              // c group

    float ss = 0.f;
    #pragma unroll
    for (int i = 0; i < 32; ++i) {
        const int cidx = i * 8 + cg;
        const float v = src[(size_t)cidx * ld + lcl];
        tile[cidx * 33 + lcl] = v;
        ss += v * v;
    }
    red[t] = ss;
    __syncthreads();
    if (t < 32) {
        float tot = 0.f;
        #pragma unroll
        for (int j = 0; j < 8; ++j) tot += red[j * 32 + t];
        linv[t] = 1.f / fmaxf(sqrtf(tot), EPSN);
    }
    __syncthreads();
    if (is_c) {
        float* dst = cn + (size_t)(n * L + l0) * C;
        #pragma unroll
        for (int j = 0; j < 32; ++j)
            dst[(size_t)j * C + t] = tile[t * 33 + j] * linv[j];   // coalesced
    } else {
        unsigned char* dst = zq + (size_t)(n * L + l0) * C;
        #pragma unroll
        for (int j = 0; j < 32; ++j)
            dst[(size_t)j * C + t] = f2fp8(tile[t * 33 + j] * linv[j]);
    }
}

// 16-channel fp8 dot: cvt_pk gives f32 PAIRS -> accumulate with packed
// v_pk_fma_f32 (v2f ext-vector arith; 2 mul + 6 pk_fma vs 16 scalar fma).
__device__ __forceinline__ float dot16(uint4 zd, float4 ca, float4 cb,
                                       float4 cc, float4 ce)
{
    const v2f c0 = {ca.x, ca.y}, c1 = {ca.z, ca.w};
    const v2f c2 = {cb.x, cb.y}, c3 = {cb.z, cb.w};
    const v2f c4 = {cc.x, cc.y}, c5 = {cc.z, cc.w};
    const v2f c6 = {ce.x, ce.y}, c7 = {ce.z, ce.w};
    v2f q, a0, a1;
    q = __builtin_amdgcn_cvt_pk_f32_fp8(zd.x, false); a0 = q * c0;
    q = __builtin_amdgcn_cvt_pk_f32_fp8(zd.x, true);  a1 = q * c1;
    q = __builtin_amdgcn_cvt_pk_f32_fp8(zd.y, false); a0 += q * c2;
    q = __builtin_amdgcn_cvt_pk_f32_fp8(zd.y, true);  a1 += q * c3;
    q = __builtin_amdgcn_cvt_pk_f32_fp8(zd.z, false); a0 += q * c4;
    q = __builtin_amdgcn_cvt_pk_f32_fp8(zd.z, true);  a1 += q * c5;
    q = __builtin_amdgcn_cvt_pk_f32_fp8(zd.w, false); a0 += q * c6;
    q = __builtin_amdgcn_cvt_pk_f32_fp8(zd.w, true);  a1 += q * c7;
    const v2f a = a0 + a1;
    return a.x + a.y;
}

// Sum one target's 16 partials (4 x float4 from LDS, in-lane, no shfl).
__device__ __forceinline__ float sumrow(const float* qp)
{
    const float4 a0 = *(const float4*)(qp);
    const float4 a1 = *(const float4*)(qp + 4);
    const float4 a2 = *(const float4*)(qp + 8);
    const float4 a3 = *(const float4*)(qp + 12);
    return ((a0.x + a0.y) + (a0.z + a0.w))
         + ((a1.x + a1.y) + (a1.z + a1.w))
         + ((a2.x + a2.y) + (a2.z + a2.w))
         + ((a3.x + a3.y) + (a3.z + a3.w));
}

// Fixed-shift LSE accumulate (logit = 2*cos <= 2) + rare exact-equal mask.
__device__ __forceinline__ void accum_target(
    int t, float dt, int row, const int* __restrict__ negp,
    const float* __restrict__ z, const float* __restrict__ c,
    float& s_acc, float& pos)
{
    const float sim2 = dt * 2.0f;
    if (t == 0) pos = sim2;
    bool use = (t <= K);
    if (use && t >= 1 && sim2 > 1.9f) {  // exact-equal mask (rare path)
        const int idxv = negp[t - 1];
        const int nr = row >> 9, lr = row & 511;
        const int ni = idxv >> 9, li = idxv & 511;
        bool eq = true;
        for (int e = 0; e < C && eq; ++e)
            eq = (c[((size_t)nr * C + e) * (L + 1) + lr + 1]
                  == z[((size_t)ni * C + e) * L + li]);
        if (eq) use = false;             // masked -inf -> contributes 0
    }
    if (use) s_acc += __expf(sim2 - 2.0f);
}

// K2: one wave per row; FOUR targets per gather wave-op (fp8 row = 256B,
// 16 lanes/target x 16B = 16 channels/lane). 104 targets (1 pos + 100 neg
// + 3 pad) in batches of 64 + 40. Phase 2: each lane owns one target,
// 4 in-lane b128 reads, no shfl.
// Tail: plain uncontended partials[] store + tiny reduce dispatch.
// NOTE (pitfall, measured r1/r3): do NOT replace this with atomics --
// 1024 relaxed same-address atomicAdds cost ~+6 us (L2 serialization);
// agent-scope acq_rel fetch_add per block costs ~+24 us (per-block L2
// writeback/invalidate cache maintenance on CDNA's flush-based coherence).
__global__ __launch_bounds__(256, 4) void logits_kernel(
    const unsigned char* __restrict__ zq, const float* __restrict__ cn,
    const int* __restrict__ neg,
    const float* __restrict__ z, const float* __restrict__ c,
    float* __restrict__ partials)
{
    __shared__ float buf[4][26 * 68];   // 16-row + 10-row batch regions
    __shared__ float wterm[4];

    const int w = threadIdx.x >> 6, lane = threadIdx.x & 63;
    const int row = __builtin_amdgcn_readfirstlane((int)blockIdx.x * 4 + w);
    const int* __restrict__ negp = neg + (size_t)row * K;
    const int g = lane >> 4;             // target within quad
    const int k = lane & 15;             // 16-channel chunk

    const float* crow = cn + (size_t)row * C + k * 16;
    const float4 ca = *(const float4*)(crow);
    const float4 cb = *(const float4*)(crow + 4);
    const float4 cc = *(const float4*)(crow + 8);
    const float4 ce = *(const float4*)(crow + 12);

    float s_acc = 0.f, pos = 0.f;
    float* __restrict__ pb0 = &buf[w][0];
    float* __restrict__ pb1 = &buf[w][16 * 68];

    // ---- batch 0: targets 0..63 (16 gather wave-ops) ----
    #pragma unroll 8
    for (int r = 0; r < 16; ++r) {
        const int t0 = 4 * r;
        const int i0 = (t0 == 0) ? row
                                 : __builtin_amdgcn_readfirstlane(negp[t0 - 1]);
        const int i1 = __builtin_amdgcn_readfirstlane(negp[t0]);
        const int i2 = __builtin_amdgcn_readfirstlane(negp[t0 + 1]);
        const int i3 = __builtin_amdgcn_readfirstlane(negp[t0 + 2]);
        const int idx = (g == 0) ? i0 : (g == 1) ? i1 : (g == 2) ? i2 : i3;
        const uint4 zd = *(const uint4*)(zq + (size_t)idx * C + k * 16);
        pb0[r * 68 + g * 16 + k] = dot16(zd, ca, cb, cc, ce); // 2-way alias: free
    }
    {   // phase 2: lane owns target t = lane
        const int t = lane;
        const float* qp = pb0 + (lane >> 2) * 68 + (lane & 3) * 16;
        accum_target(t, sumrow(qp), row, negp, z, c, s_acc, pos);
    }

    // ---- batch 1: targets 64..103 (10 gather wave-ops, 101..103 = pad) ----
    #pragma unroll 8
    for (int r = 0; r < 10; ++r) {
        const int t0 = 64 + 4 * r;
        const int i0 = __builtin_amdgcn_readfirstlane(negp[t0 - 1]);
        const int i1 = (t0 + 1 <= K) ? __builtin_amdgcn_readfirstlane(negp[t0]) : row;
        const int i2 = (t0 + 2 <= K) ? __builtin_amdgcn_readfirstlane(negp[t0 + 1]) : row;
        const int i3 = (t0 + 3 <= K) ? __builtin_amdgcn_readfirstlane(negp[t0 + 2]) : row;
        const int idx = (g == 0) ? i0 : (g == 1) ? i1 : (g == 2) ? i2 : i3;
        const uint4 zd = *(const uint4*)(zq + (size_t)idx * C + k * 16);
        pb1[r * 68 + g * 16 + k] = dot16(zd, ca, cb, cc, ce);
    }
    {   // phase 2: lanes 0..39 own targets 64..103; rest masked by t<=K
        const int t = 64 + lane;
        const int pr = (lane >> 2) < 10 ? (lane >> 2) : 0;  // clamp: masked lanes
        const float* qp = pb1 + pr * 68 + (lane & 3) * 16;
        accum_target(t, sumrow(qp), row, negp, z, c, s_acc, pos);
    }

    #pragma unroll
    for (int m = 1; m < 64; m <<= 1) s_acc += __shfl_xor(s_acc, m, 64);
    if (lane == 0) wterm[w] = 2.0f + __logf(s_acc) - pos;
    __syncthreads();
    if (threadIdx.x == 0)
        partials[blockIdx.x] = wterm[0] + wterm[1] + wterm[2] + wterm[3];
}

// K3: reduce 1024 block partials -> mean loss.
__global__ __launch_bounds__(256) void reduce_kernel(
    const float* __restrict__ p, float* __restrict__ out)
{
    __shared__ float red[4];
    const int t = threadIdx.x;
    float s = p[t] + p[t + 256] + p[t + 512] + p[t + 768];
    #pragma unroll
    for (int m = 1; m < 64; m <<= 1) s += __shfl_xor(s, m, 64);
    if ((t & 63) == 0) red[t >> 6] = s;
    __syncthreads();
    if (t == 0) out[0] = (red[0] + red[1] + red[2] + red[3]) * (1.0f / NL);
}

extern "C" void kernel_launch(void* const* d_in, const int* in_sizes, int n_in,
                              void* d_out, int out_size, void* d_ws, size_t ws_size,
                              hipStream_t stream) {
    const float* z = (const float*)d_in[0];
    const float* c = (const float*)d_in[1];
    const int* neg = (const int*)d_in[2];
    float* out = (float*)d_out;

    float* cn = (float*)d_ws;
    unsigned char* zq = (unsigned char*)(cn + (size_t)NL * C);
    float* partials = (float*)(zq + (size_t)NL * C);

    prep_kernel<<<256, 256, 0, stream>>>(z, c, zq, cn);
    logits_kernel<<<NL / 4, 256, 0, stream>>>(zq, cn, neg, z, c, partials);
    reduce_kernel<<<1, 256, 0, stream>>>(partials, out);
}